// Round 15
// baseline (119.795 us; speedup 1.0000x reference)
//
#include <hip/hip_runtime.h>
#include <math.h>

typedef _Float16 half8 __attribute__((ext_vector_type(8)));
typedef float f32x4 __attribute__((ext_vector_type(4)));

// dims
constexpr int B_ = 8;
constexpr int HG = 160, WG = 320;          // guidance spatial
constexpr int H = 80, W = 160;             // x spatial
// ws layout (bytes)
constexpr size_t CWS_OFF  = 0;             // 4 ng * 165888 = 663552
constexpr size_t W1WS_OFF = 663552;        // 9 taps * 4096 = 36864
constexpr size_t XG_OFF   = 700416;        // 8*80*160*64*2 = 13107200

// ---------------------------------------------------------------------------
// prep: weight tensors -> MFMA B-operand register images (one thread per
// (n, cin), reading 9 contiguous taps).   (R8 version, unchanged)
// conv2: Cws [ng][18 s][9 k][1024B]; lane = grp*16+nl (grp=kl>>3, nl=n&15)
//   holds bytes [lane*16,lane*16+16) = kl j=grp*8..+8. K = t*64+cin ->
//   s = 2t + (cin>>5), kl = cin&31.
// conv1: w1ws [t=9][nt 4][1024B]; same image with kl=cin(32), nl=ch&15.
// ---------------------------------------------------------------------------
__global__ __launch_bounds__(256) void prep(const float* __restrict__ w1,
                                            const float* __restrict__ w2,
                                            char* __restrict__ ws)
{
    int e = blockIdx.x * 256 + threadIdx.x;
    if (e < 576 * 64) {
        int n = e >> 6, cin = e & 63;
        int k = n >> 6, ng = (n >> 4) & 3, nl = n & 15;
        int kl = cin & 31, c5 = cin >> 5;
        const float* src = w2 + ((size_t)(n * 64 + cin)) * 9;
        int fragoff = ((kl >> 3) * 16 + nl) * 16 + (kl & 7) * 2;
#pragma unroll
        for (int t = 0; t < 9; ++t) {
            int s = t * 2 + c5;
            *(_Float16*)(ws + CWS_OFF + (size_t)ng * 165888
                         + (size_t)(s * 9 + k) * 1024 + fragoff) = (_Float16)src[t];
        }
    } else if (e < 576 * 64 + 64 * 32) {
        int e2 = e - 576 * 64;
        int ch = e2 >> 5, cin = e2 & 31;
        const float* src = w1 + ((size_t)(ch * 32 + cin)) * 9;
        int fragoff = (ch >> 4) * 1024 + ((cin >> 3) * 16 + (ch & 15)) * 16 + (cin & 7) * 2;
#pragma unroll
        for (int t = 0; t < 9; ++t)
            *(_Float16*)(ws + W1WS_OFF + (size_t)t * 4096 + fragoff) = (_Float16)src[t];
    }
}

// ---------------------------------------------------------------------------
// conv1 (3x3 s2 p1, 32->64) + BN + ReLU via MFMA. Output f16 NHWC.
// (R8 version, unchanged)
// ---------------------------------------------------------------------------
__global__ __launch_bounds__(256, 4) void conv1_mfma(
    const float* __restrict__ g, const char* __restrict__ ws_w1,
    const float* __restrict__ gamma, const float* __restrict__ beta,
    const float* __restrict__ mean, const float* __restrict__ var,
    _Float16* __restrict__ xg)
{
    const int tx0 = blockIdx.x * 16, ty0 = blockIdx.y * 8, b = blockIdx.z;
    __shared__ __align__(16) _Float16 gl[2][17][18][32];   // 39168 B
    const int tid = threadIdx.x;

    const int gy0 = 2 * ty0 - 1;
    const int gxa0 = 2 * tx0 - 2;
    for (int i = tid; i < 17 * 32 * 17; i += 256) {
        int wr = i / 544; int rem = i - wr * 544;
        int cin = rem / 17; int c2 = rem - cin * 17;
        int gy = gy0 + wr;
        int gxa = gxa0 + 2 * c2;
        float2 v = make_float2(0.f, 0.f);
        if (gy >= 0 && gy < HG && gxa >= 0)
            v = *(const float2*)(g + ((size_t)(b * 32 + cin) * HG + gy) * WG + gxa);
        int slot = cin >> 3, elem = cin & 7;
        if (c2 > 0) {
            int wch = c2 - 1;
            gl[1][wr][wch][((slot ^ ((wch >> 1) & 3)) << 3) + elem] = (_Float16)v.x;
        }
        {
            int wch = c2;
            gl[0][wr][wch][((slot ^ ((wch >> 1) & 3)) << 3) + elem] = (_Float16)v.y;
        }
    }

    const int lane = tid & 63, w = tid >> 6;
    const int c = lane & 15, grp = lane >> 4;

    const _Float16* w1p = (const _Float16*)ws_w1 + lane * 8;
    half8 bf[4];
#pragma unroll
    for (int nt = 0; nt < 4; ++nt) bf[nt] = *(const half8*)(w1p + nt * 512);

    f32x4 zf = {0.f, 0.f, 0.f, 0.f};
    f32x4 acc[2][4];
#pragma unroll
    for (int mt = 0; mt < 2; ++mt)
#pragma unroll
        for (int nt = 0; nt < 4; ++nt) acc[mt][nt] = zf;

    __syncthreads();   // gl ready; no further barriers

#pragma unroll
    for (int s = 0; s < 9; ++s) {
        const int dy = s / 3, dx = s - dy * 3;
        const int par = dx & 1, dxh = dx >> 1;
        half8 af[2];
#pragma unroll
        for (int mt = 0; mt < 2; ++mt) {
            int wr = 2 * (2 * w + mt) + dy;
            int wch = c + dxh;
            af[mt] = *(const half8*)&gl[par][wr][wch][(grp ^ ((wch >> 1) & 3)) << 3];
        }
        const _Float16* wnext = w1p + (size_t)(s + 1) * 2048;
#pragma unroll
        for (int nt = 0; nt < 4; ++nt) {
            half8 cur = bf[nt];
            bf[nt] = *(const half8*)(wnext + nt * 512);   // s=8 overread harmless
            acc[0][nt] = __builtin_amdgcn_mfma_f32_16x16x32_f16(af[0], cur, acc[0][nt], 0, 0, 0);
            acc[1][nt] = __builtin_amdgcn_mfma_f32_16x16x32_f16(af[1], cur, acc[1][nt], 0, 0, 0);
        }
    }

#pragma unroll
    for (int nt = 0; nt < 4; ++nt) {
        int ch = nt * 16 + c;
        float mu = mean[ch], scv = rsqrtf(var[ch] + 1e-5f) * gamma[ch], bt = beta[ch];
#pragma unroll
        for (int mt = 0; mt < 2; ++mt) {
            int y = ty0 + 2 * w + mt;
#pragma unroll
            for (int r = 0; r < 4; ++r) {
                int x = tx0 + grp * 4 + r;
                float v = fmaxf((acc[mt][nt][r] - mu) * scv + bt, 0.f);
                xg[(((size_t)(b * H + y) * W + x) << 6) + ch] = (_Float16)v;
            }
        }
    }
}

// ---------------------------------------------------------------------------
// conv2 k-half core: K-loop (NK fragments, k = KB..KB+NK-1) + partial softmax
// {m, S=sum e, U=sum e*pat}. kh0 (KB=0) combines with partner via LDS and
// stores; kh1 (KB=5) writes its partials to LDS.
// NOTE: each branch executes exactly one __syncthreads() (all 4 waves reach
// a barrier once -> HW wave-counting barrier matches).
// ---------------------------------------------------------------------------
template<int KB, int NK>
__device__ __forceinline__ void conv2_half(
    const _Float16* __restrict__ wp, const _Float16* __restrict__ xs,
    const float* __restrict__ d8s, float (*part)[4][16][16][4],
    int c, int grp, int ngl, int ng, int s0, int b, int tx0, int ty0,
    float* __restrict__ out)
{
    f32x4 zf = {0.f, 0.f, 0.f, 0.f};
    f32x4 acc[4][NK];
#pragma unroll
    for (int m = 0; m < 4; ++m)
#pragma unroll
        for (int f = 0; f < NK; ++f) acc[m][f] = zf;

    half8 bf[NK];
#pragma unroll
    for (int f = 0; f < NK; ++f)
        bf[f] = *(const half8*)(wp + (size_t)s0 * 4608 + (KB + f) * 512);

    int s = s0;
#pragma unroll 2
    for (int i = 0; i < 18; ++i) {
        int sn = s + 1; if (sn == 18) sn = 0;
        const int t = s >> 1;
        const int dy = t / 3, dx = t - dy * 3;
        const int aslot = (s & 1) * 4 + grp;
        half8 af[4];
#pragma unroll
        for (int mt = 0; mt < 4; ++mt) {
            int wrow = (mt + dy) * 18 + c + dx;
            af[mt] = *(const half8*)&xs[wrow * 64 + (aslot ^ (wrow & 7)) * 8];
        }
        const _Float16* wnext = wp + (size_t)sn * 4608;
#pragma unroll
        for (int f = 0; f < NK; ++f) {
            half8 cur = bf[f];
            bf[f] = *(const half8*)(wnext + (KB + f) * 512);   // wrap load valid
#pragma unroll
            for (int mt = 0; mt < 4; ++mt)
                acc[mt][f] = __builtin_amdgcn_mfma_f32_16x16x32_f16(
                    af[mt], cur, acc[mt][f], 0, 0, 0);
        }
        s = sn;
    }

    if (KB != 0) {
        // kh1: partials -> LDS, then barrier
#pragma unroll
        for (int mt = 0; mt < 4; ++mt) {
#pragma unroll
            for (int r = 0; r < 4; ++r) {
                const int pc = grp * 4 + r;
                float m = acc[mt][0][r];
#pragma unroll
                for (int f = 1; f < NK; ++f) m = fmaxf(m, acc[mt][f][r]);
                float S = 0.f, U = 0.f;
#pragma unroll
                for (int f = 0; f < NK; ++f) {
                    const int k = KB + f;
                    float e = __expf(acc[mt][f][r] - m);
                    S += e;
                    U += e * d8s[(mt + k / 3) * 18 + pc + k % 3];
                }
                float4 pv = make_float4(m, S, U, 0.f);
                *(float4*)&part[ngl][mt][pc][c][0] = pv;
            }
        }
        __syncthreads();
    } else {
        // kh0: partials in regs, barrier, combine with partner, store
        float pm[4][4], pS[4][4], pU[4][4];
#pragma unroll
        for (int mt = 0; mt < 4; ++mt) {
#pragma unroll
            for (int r = 0; r < 4; ++r) {
                const int pc = grp * 4 + r;
                float m = acc[mt][0][r];
#pragma unroll
                for (int f = 1; f < NK; ++f) m = fmaxf(m, acc[mt][f][r]);
                float S = 0.f, U = 0.f;
#pragma unroll
                for (int f = 0; f < NK; ++f) {
                    const int k = KB + f;
                    float e = __expf(acc[mt][f][r] - m);
                    S += e;
                    U += e * d8s[(mt + k / 3) * 18 + pc + k % 3];
                }
                pm[mt][r] = m; pS[mt][r] = S; pU[mt][r] = U;
            }
        }
        __syncthreads();
        const int ij = ng * 16 + c;
        const int oi = ij >> 3, oj = ij & 7;
#pragma unroll
        for (int mt = 0; mt < 4; ++mt) {
#pragma unroll
            for (int r = 0; r < 4; ++r) {
                const int pc = grp * 4 + r;
                float4 pv = *(const float4*)&part[ngl][mt][pc][c][0];
                float mt_ = fmaxf(pm[mt][r], pv.x);
                float e0 = __expf(pm[mt][r] - mt_);
                float e1 = __expf(pv.x - mt_);
                float sum = pS[mt][r] * e0 + pv.y * e1;
                float up  = pU[mt][r] * e0 + pv.z * e1;
                int y = ty0 + mt, xc = tx0 + pc;
                out[((size_t)(b * (8 * H) + y * 8 + oi)) * (size_t)(8 * W)
                    + xc * 8 + oj] = up / sum;
            }
        }
    }
}

// ---------------------------------------------------------------------------
// conv2 (3x3 s1 p1, 64->576) + softmax(9) + convex combine + pixel shuffle.
// K-SPLIT WAVE PAIRS: block = 4 waves = 2 ngl x 2 kh over a 16x4 px tile and
// 32 ij (half of 64; grid x carries the ij-half h). Each wave: Mt=4,
// register-direct B (its 4-5 k-fragments of ng = h*2+ngl), ring-offset K
// order, no K-loop barriers. acc<=80+bf 20 -> ~160 total regs ->
// 3 waves/SIMD. Softmax = two lane-local partials combined via 32KB LDS.
// (R14 with the xs staging loop reverted to R13's proven 864-iter form —
// R14's 576-iter rewrite overflowed xs into d8s/part.)
// ---------------------------------------------------------------------------
__global__ __launch_bounds__(256, 3) void conv2_mfma(
    const _Float16* __restrict__ xg, const char* __restrict__ ws_c,
    const float* __restrict__ disp, float* __restrict__ out)
{
    const int h = blockIdx.x & 1;
    const int tx0 = (blockIdx.x >> 1) * 16, ty0 = blockIdx.y * 4, b = blockIdx.z;
    __shared__ __align__(16) _Float16 xs[108 * 64];       // 13824 B
    __shared__ float d8s[108];
    __shared__ __align__(16) float part[2][4][16][16][4]; // 32768 B
    const int tid = threadIdx.x;
    const int lane = tid & 63, wid = tid >> 6;
    const int c = lane & 15, grp = lane >> 4;
    const int ngl = wid & 1, kh = wid >> 1;
    const int ng = h * 2 + ngl;

    // stage x window 6x18x64 f16, swizzled: 16B slot' = slot ^ (wp&7)
    // (R13's proven loop: one half8 per iteration, cidx < 108*8 = 864)
    half8 zero8;
#pragma unroll
    for (int j = 0; j < 8; ++j) zero8[j] = (_Float16)0.f;
    for (int cidx = tid; cidx < 864; cidx += 256) {
        int wpx = cidx >> 3, slot = cidx & 7;
        int rr = wpx / 18, cc = wpx - rr * 18;
        int y = ty0 - 1 + rr, xc = tx0 - 1 + cc;
        half8 v = zero8;
        if (y >= 0 && y < H && xc >= 0 && xc < W)
            v = *(const half8*)(xg + (((size_t)(b * H + y) * W + xc) << 6) + slot * 8);
        *(half8*)&xs[wpx * 64 + (slot ^ (wpx & 7)) * 8] = v;
    }
    if (tid < 108) {
        int rr = tid / 18, cc = tid - rr * 18;
        int y = ty0 - 1 + rr, xc = tx0 - 1 + cc;
        float v = 0.f;
        if (y >= 0 && y < H && xc >= 0 && xc < W) v = 8.f * disp[(b * H + y) * W + xc];
        d8s[tid] = v;
    }

    // ring start offset: decorrelate co-resident blocks' phases
    const int lb = (blockIdx.z * 20 + blockIdx.y) * 20 + blockIdx.x;
    const int s0 = (lb * 7) % 18;

    // this wave's weight stream: ng slice, [18 s][9 k][1024B], lane*16 B
    const _Float16* wp = (const _Float16*)ws_c + (size_t)ng * 82944 + lane * 8;

    __syncthreads();   // xs, d8s ready

    if (kh == 0)
        conv2_half<0, 5>(wp, xs, d8s, part, c, grp, ngl, ng, s0, b, tx0, ty0, out);
    else
        conv2_half<5, 4>(wp, xs, d8s, part, c, grp, ngl, ng, s0, b, tx0, ty0, out);
}

// ---------------------------------------------------------------------------
extern "C" void kernel_launch(void* const* d_in, const int* in_sizes, int n_in,
                              void* d_out, int out_size, void* d_ws, size_t ws_size,
                              hipStream_t stream)
{
    const float* guidance = (const float*)d_in[0];
    const float* disp     = (const float*)d_in[1];
    const float* conv1_w  = (const float*)d_in[2];
    const float* bn_gamma = (const float*)d_in[3];
    const float* bn_beta  = (const float*)d_in[4];
    const float* bn_mean  = (const float*)d_in[5];
    const float* bn_var   = (const float*)d_in[6];
    const float* conv2_w  = (const float*)d_in[7];
    float* out = (float*)d_out;
    char* ws = (char*)d_ws;
    _Float16* xg = (_Float16*)(ws + XG_OFF);

    prep<<<dim3((576 * 64 + 64 * 32 + 255) / 256), dim3(256), 0, stream>>>(
        conv1_w, conv2_w, ws);
    dim3 grid1(W / 16, H / 8, B_);   // (10, 10, 8)
    conv1_mfma<<<grid1, dim3(256), 0, stream>>>(
        guidance, ws + W1WS_OFF, bn_gamma, bn_beta, bn_mean, bn_var, xg);
    dim3 grid2(2 * W / 16, H / 4, B_);   // (20, 20, 8): x = px-tile*2 + ij-half
    conv2_mfma<<<grid2, dim3(256), 0, stream>>>(
        xg, ws + CWS_OFF, disp, out);
}

// Round 16
// 107.295 us; speedup vs baseline: 1.1165x; 1.1165x over previous
//
#include <hip/hip_runtime.h>
#include <math.h>

typedef _Float16 half8 __attribute__((ext_vector_type(8)));
typedef float f32x4 __attribute__((ext_vector_type(4)));

// dims
constexpr int B_ = 8;
constexpr int HG = 160, WG = 320;          // guidance spatial
constexpr int H = 80, W = 160;             // x spatial
// ws layout (bytes)
constexpr size_t CWS_OFF  = 0;             // 4 ng * 165888 = 663552
constexpr size_t W1WS_OFF = 663552;        // 9 taps * 4096 = 36864
constexpr size_t XG_OFF   = 700416;        // 8*80*160*64*2 = 13107200

// ---------------------------------------------------------------------------
// prep: weight tensors -> MFMA B-operand register images (one thread per
// (n, cin), reading 9 contiguous taps).   (R8 version, unchanged)
// conv2: Cws [ng][18 s][9 k][1024B]; lane = grp*16+nl (grp=kl>>3, nl=n&15)
//   holds bytes [lane*16,lane*16+16) = kl j=grp*8..+8. K = t*64+cin ->
//   s = 2t + (cin>>5), kl = cin&31.
// conv1: w1ws [t=9][nt 4][1024B]; same image with kl=cin(32), nl=ch&15.
// ---------------------------------------------------------------------------
__global__ __launch_bounds__(256) void prep(const float* __restrict__ w1,
                                            const float* __restrict__ w2,
                                            char* __restrict__ ws)
{
    int e = blockIdx.x * 256 + threadIdx.x;
    if (e < 576 * 64) {
        int n = e >> 6, cin = e & 63;
        int k = n >> 6, ng = (n >> 4) & 3, nl = n & 15;
        int kl = cin & 31, c5 = cin >> 5;
        const float* src = w2 + ((size_t)(n * 64 + cin)) * 9;
        int fragoff = ((kl >> 3) * 16 + nl) * 16 + (kl & 7) * 2;
#pragma unroll
        for (int t = 0; t < 9; ++t) {
            int s = t * 2 + c5;
            *(_Float16*)(ws + CWS_OFF + (size_t)ng * 165888
                         + (size_t)(s * 9 + k) * 1024 + fragoff) = (_Float16)src[t];
        }
    } else if (e < 576 * 64 + 64 * 32) {
        int e2 = e - 576 * 64;
        int ch = e2 >> 5, cin = e2 & 31;
        const float* src = w1 + ((size_t)(ch * 32 + cin)) * 9;
        int fragoff = (ch >> 4) * 1024 + ((cin >> 3) * 16 + (ch & 15)) * 16 + (cin & 7) * 2;
#pragma unroll
        for (int t = 0; t < 9; ++t)
            *(_Float16*)(ws + W1WS_OFF + (size_t)t * 4096 + fragoff) = (_Float16)src[t];
    }
}

// ---------------------------------------------------------------------------
// conv1 (3x3 s2 p1, 32->64) + BN + ReLU via MFMA. Output f16 NHWC.
// (R8 version, unchanged)
// ---------------------------------------------------------------------------
__global__ __launch_bounds__(256, 4) void conv1_mfma(
    const float* __restrict__ g, const char* __restrict__ ws_w1,
    const float* __restrict__ gamma, const float* __restrict__ beta,
    const float* __restrict__ mean, const float* __restrict__ var,
    _Float16* __restrict__ xg)
{
    const int tx0 = blockIdx.x * 16, ty0 = blockIdx.y * 8, b = blockIdx.z;
    __shared__ __align__(16) _Float16 gl[2][17][18][32];   // 39168 B
    const int tid = threadIdx.x;

    const int gy0 = 2 * ty0 - 1;
    const int gxa0 = 2 * tx0 - 2;
    for (int i = tid; i < 17 * 32 * 17; i += 256) {
        int wr = i / 544; int rem = i - wr * 544;
        int cin = rem / 17; int c2 = rem - cin * 17;
        int gy = gy0 + wr;
        int gxa = gxa0 + 2 * c2;
        float2 v = make_float2(0.f, 0.f);
        if (gy >= 0 && gy < HG && gxa >= 0)
            v = *(const float2*)(g + ((size_t)(b * 32 + cin) * HG + gy) * WG + gxa);
        int slot = cin >> 3, elem = cin & 7;
        if (c2 > 0) {
            int wch = c2 - 1;
            gl[1][wr][wch][((slot ^ ((wch >> 1) & 3)) << 3) + elem] = (_Float16)v.x;
        }
        {
            int wch = c2;
            gl[0][wr][wch][((slot ^ ((wch >> 1) & 3)) << 3) + elem] = (_Float16)v.y;
        }
    }

    const int lane = tid & 63, w = tid >> 6;
    const int c = lane & 15, grp = lane >> 4;

    const _Float16* w1p = (const _Float16*)ws_w1 + lane * 8;
    half8 bf[4];
#pragma unroll
    for (int nt = 0; nt < 4; ++nt) bf[nt] = *(const half8*)(w1p + nt * 512);

    f32x4 zf = {0.f, 0.f, 0.f, 0.f};
    f32x4 acc[2][4];
#pragma unroll
    for (int mt = 0; mt < 2; ++mt)
#pragma unroll
        for (int nt = 0; nt < 4; ++nt) acc[mt][nt] = zf;

    __syncthreads();   // gl ready; no further barriers

#pragma unroll
    for (int s = 0; s < 9; ++s) {
        const int dy = s / 3, dx = s - dy * 3;
        const int par = dx & 1, dxh = dx >> 1;
        half8 af[2];
#pragma unroll
        for (int mt = 0; mt < 2; ++mt) {
            int wr = 2 * (2 * w + mt) + dy;
            int wch = c + dxh;
            af[mt] = *(const half8*)&gl[par][wr][wch][(grp ^ ((wch >> 1) & 3)) << 3];
        }
        const _Float16* wnext = w1p + (size_t)(s + 1) * 2048;
#pragma unroll
        for (int nt = 0; nt < 4; ++nt) {
            half8 cur = bf[nt];
            bf[nt] = *(const half8*)(wnext + nt * 512);   // s=8 overread harmless
            acc[0][nt] = __builtin_amdgcn_mfma_f32_16x16x32_f16(af[0], cur, acc[0][nt], 0, 0, 0);
            acc[1][nt] = __builtin_amdgcn_mfma_f32_16x16x32_f16(af[1], cur, acc[1][nt], 0, 0, 0);
        }
    }

#pragma unroll
    for (int nt = 0; nt < 4; ++nt) {
        int ch = nt * 16 + c;
        float mu = mean[ch], scv = rsqrtf(var[ch] + 1e-5f) * gamma[ch], bt = beta[ch];
#pragma unroll
        for (int mt = 0; mt < 2; ++mt) {
            int y = ty0 + 2 * w + mt;
#pragma unroll
            for (int r = 0; r < 4; ++r) {
                int x = tx0 + grp * 4 + r;
                float v = fmaxf((acc[mt][nt][r] - mu) * scv + bt, 0.f);
                xg[(((size_t)(b * H + y) * W + x) << 6) + ch] = (_Float16)v;
            }
        }
    }
}

// ---------------------------------------------------------------------------
// conv2 (3x3 s1 p1, 64->576) + softmax(9) + convex combine + pixel shuffle.
// PERSISTENT R13 engine + scheduler levers: 512 blocks (2/CU), tiles
// bid, bid+512, ... Per tile: 16x4 px, 4 waves (wave = ng, k-complete per
// lane -> lane-local softmax), Mt=4, register-direct B stream, ring-offset
// K order (s0 = tile*7 mod 18), no K-loop barriers.
// NEW vs R13: s_setprio(1) around each step's 36-MFMA cluster (T5 — pays
// only with role-split waves, which the ring desync provides) and FULL
// unroll of the 18-step loop (removes branch scheduling fences).
// ---------------------------------------------------------------------------
__global__ __launch_bounds__(256, 2) void conv2_mfma(
    const _Float16* __restrict__ xg, const char* __restrict__ ws_c,
    const float* __restrict__ disp, float* __restrict__ out)
{
    __shared__ __align__(16) _Float16 xs[108 * 64];   // 6r x 18c x 64ch, 13824 B
    __shared__ float d8s[108];
    const int tid = threadIdx.x;
    const int lane = tid & 63, wid = tid >> 6;
    const int c = lane & 15, grp = lane >> 4;

    // this wave's weight stream: [18 s][9 k][1024B], lane slice = lane*16 B
    const _Float16* wp = (const _Float16*)ws_c + (size_t)wid * 82944 + lane * 8;

    half8 zero8;
#pragma unroll
    for (int j = 0; j < 8; ++j) zero8[j] = (_Float16)0.f;

    for (int tile = blockIdx.x; tile < 1600; tile += 512) {
        const int b   = tile / 200;
        const int rem = tile - b * 200;
        const int tyi = rem / 10;
        const int tx0 = (rem - tyi * 10) * 16, ty0 = tyi * 4;
        const int s0  = (tile * 7) % 18;

        __syncthreads();   // guard xs/d8s overwrite vs prior tile's readers

        // stage x window 6x18x64 f16, swizzled: 16B slot' = slot ^ (wp&7)
        for (int cidx = tid; cidx < 864; cidx += 256) {
            int wpx = cidx >> 3, slot = cidx & 7;
            int rr = wpx / 18, cc = wpx - rr * 18;
            int y = ty0 - 1 + rr, xc = tx0 - 1 + cc;
            half8 v = zero8;
            if (y >= 0 && y < H && xc >= 0 && xc < W)
                v = *(const half8*)(xg + (((size_t)(b * H + y) * W + xc) << 6) + slot * 8);
            *(half8*)&xs[wpx * 64 + (slot ^ (wpx & 7)) * 8] = v;
        }
        if (tid < 108) {
            int rr = tid / 18, cc = tid - rr * 18;
            int y = ty0 - 1 + rr, xc = tx0 - 1 + cc;
            float v = 0.f;
            if (y >= 0 && y < H && xc >= 0 && xc < W) v = 8.f * disp[(b * H + y) * W + xc];
            d8s[tid] = v;
        }

        f32x4 zf = {0.f, 0.f, 0.f, 0.f};
        f32x4 acc[4][9];
#pragma unroll
        for (int m = 0; m < 4; ++m)
#pragma unroll
            for (int k = 0; k < 9; ++k) acc[m][k] = zf;

        half8 bf[9];
#pragma unroll
        for (int k = 0; k < 9; ++k)
            bf[k] = *(const half8*)(wp + (size_t)s0 * 4608 + k * 512);

        __syncthreads();   // xs, d8s ready

        int s = s0;
#pragma unroll
        for (int i = 0; i < 18; ++i) {
            int sn = s + 1; if (sn == 18) sn = 0;
            const int t = s >> 1;
            const int dy = t / 3, dx = t - dy * 3;
            const int aslot = (s & 1) * 4 + grp;
            half8 af[4];
#pragma unroll
            for (int mt = 0; mt < 4; ++mt) {
                int wrow = (mt + dy) * 18 + c + dx;
                af[mt] = *(const half8*)&xs[wrow * 64 + (aslot ^ (wrow & 7)) * 8];
            }
            const _Float16* wnext = wp + (size_t)sn * 4608;
            __builtin_amdgcn_s_setprio(1);
#pragma unroll
            for (int k = 0; k < 9; ++k) {
                half8 cur = bf[k];
                // prefetch ring-next step's fragment k (wrap load unused, valid)
                bf[k] = *(const half8*)(wnext + k * 512);
#pragma unroll
                for (int mt = 0; mt < 4; ++mt)
                    acc[mt][k] = __builtin_amdgcn_mfma_f32_16x16x32_f16(
                        af[mt], cur, acc[mt][k], 0, 0, 0);
            }
            __builtin_amdgcn_s_setprio(0);
            s = sn;
        }

        // epilogue: lane-local softmax over 9 k per (pixel, ij)
        const int ij = wid * 16 + c;
        const int oi = ij >> 3, oj = ij & 7;
#pragma unroll
        for (int mt = 0; mt < 4; ++mt) {
#pragma unroll
            for (int r = 0; r < 4; ++r) {
                int pr = mt, pc = grp * 4 + r;
                float pat[9];
#pragma unroll
                for (int k9 = 0; k9 < 9; ++k9) pat[k9] = d8s[(pr + k9 / 3) * 18 + pc + k9 % 3];
                float mx = acc[mt][0][r];
#pragma unroll
                for (int k9 = 1; k9 < 9; ++k9) mx = fmaxf(mx, acc[mt][k9][r]);
                float sum = 0.f, up = 0.f;
#pragma unroll
                for (int k9 = 0; k9 < 9; ++k9) {
                    float e = __expf(acc[mt][k9][r] - mx);
                    sum += e; up += e * pat[k9];
                }
                int y = ty0 + pr, xc = tx0 + pc;
                out[((size_t)(b * (8 * H) + y * 8 + oi)) * (size_t)(8 * W) + xc * 8 + oj] = up / sum;
            }
        }
    }
}

// ---------------------------------------------------------------------------
extern "C" void kernel_launch(void* const* d_in, const int* in_sizes, int n_in,
                              void* d_out, int out_size, void* d_ws, size_t ws_size,
                              hipStream_t stream)
{
    const float* guidance = (const float*)d_in[0];
    const float* disp     = (const float*)d_in[1];
    const float* conv1_w  = (const float*)d_in[2];
    const float* bn_gamma = (const float*)d_in[3];
    const float* bn_beta  = (const float*)d_in[4];
    const float* bn_mean  = (const float*)d_in[5];
    const float* bn_var   = (const float*)d_in[6];
    const float* conv2_w  = (const float*)d_in[7];
    float* out = (float*)d_out;
    char* ws = (char*)d_ws;
    _Float16* xg = (_Float16*)(ws + XG_OFF);

    prep<<<dim3((576 * 64 + 64 * 32 + 255) / 256), dim3(256), 0, stream>>>(
        conv1_w, conv2_w, ws);
    dim3 grid1(W / 16, H / 8, B_);   // (10, 10, 8)
    conv1_mfma<<<grid1, dim3(256), 0, stream>>>(
        guidance, ws + W1WS_OFF, bn_gamma, bn_beta, bn_mean, bn_var, xg);
    conv2_mfma<<<dim3(512), dim3(256), 0, stream>>>(
        xg, ws + CWS_OFF, disp, out);
}

// Round 17
// 106.635 us; speedup vs baseline: 1.1234x; 1.0062x over previous
//
#include <hip/hip_runtime.h>
#include <math.h>

typedef _Float16 half8 __attribute__((ext_vector_type(8)));
typedef float f32x4 __attribute__((ext_vector_type(4)));

// dims
constexpr int B_ = 8;
constexpr int HG = 160, WG = 320;          // guidance spatial
constexpr int H = 80, W = 160;             // x spatial
// ws layout (bytes)
constexpr size_t CWS_OFF  = 0;             // 4 ng * 165888 = 663552
constexpr size_t W1WS_OFF = 663552;        // 9 taps * 4096 = 36864
constexpr size_t XG_OFF   = 700416;        // 8*80*160*64*2 = 13107200

// ---------------------------------------------------------------------------
// prep: weight tensors -> MFMA B-operand register images (one thread per
// (n, cin), reading 9 contiguous taps).   (R8 version, unchanged)
// conv2: Cws [ng][18 s][9 k][1024B]; lane = grp*16+nl (grp=kl>>3, nl=n&15)
//   holds bytes [lane*16,lane*16+16) = kl j=grp*8..+8. K = t*64+cin ->
//   s = 2t + (cin>>5), kl = cin&31.
// conv1: w1ws [t=9][nt 4][1024B]; same image with kl=cin(32), nl=ch&15.
// ---------------------------------------------------------------------------
__global__ __launch_bounds__(256) void prep(const float* __restrict__ w1,
                                            const float* __restrict__ w2,
                                            char* __restrict__ ws)
{
    int e = blockIdx.x * 256 + threadIdx.x;
    if (e < 576 * 64) {
        int n = e >> 6, cin = e & 63;
        int k = n >> 6, ng = (n >> 4) & 3, nl = n & 15;
        int kl = cin & 31, c5 = cin >> 5;
        const float* src = w2 + ((size_t)(n * 64 + cin)) * 9;
        int fragoff = ((kl >> 3) * 16 + nl) * 16 + (kl & 7) * 2;
#pragma unroll
        for (int t = 0; t < 9; ++t) {
            int s = t * 2 + c5;
            *(_Float16*)(ws + CWS_OFF + (size_t)ng * 165888
                         + (size_t)(s * 9 + k) * 1024 + fragoff) = (_Float16)src[t];
        }
    } else if (e < 576 * 64 + 64 * 32) {
        int e2 = e - 576 * 64;
        int ch = e2 >> 5, cin = e2 & 31;
        const float* src = w1 + ((size_t)(ch * 32 + cin)) * 9;
        int fragoff = (ch >> 4) * 1024 + ((cin >> 3) * 16 + (ch & 15)) * 16 + (cin & 7) * 2;
#pragma unroll
        for (int t = 0; t < 9; ++t)
            *(_Float16*)(ws + W1WS_OFF + (size_t)t * 4096 + fragoff) = (_Float16)src[t];
    }
}

// ---------------------------------------------------------------------------
// conv1 (3x3 s2 p1, 32->64) + BN + ReLU via MFMA. Output f16 NHWC.
// (R8 version, unchanged)
// ---------------------------------------------------------------------------
__global__ __launch_bounds__(256, 4) void conv1_mfma(
    const float* __restrict__ g, const char* __restrict__ ws_w1,
    const float* __restrict__ gamma, const float* __restrict__ beta,
    const float* __restrict__ mean, const float* __restrict__ var,
    _Float16* __restrict__ xg)
{
    const int tx0 = blockIdx.x * 16, ty0 = blockIdx.y * 8, b = blockIdx.z;
    __shared__ __align__(16) _Float16 gl[2][17][18][32];   // 39168 B
    const int tid = threadIdx.x;

    const int gy0 = 2 * ty0 - 1;
    const int gxa0 = 2 * tx0 - 2;
    for (int i = tid; i < 17 * 32 * 17; i += 256) {
        int wr = i / 544; int rem = i - wr * 544;
        int cin = rem / 17; int c2 = rem - cin * 17;
        int gy = gy0 + wr;
        int gxa = gxa0 + 2 * c2;
        float2 v = make_float2(0.f, 0.f);
        if (gy >= 0 && gy < HG && gxa >= 0)
            v = *(const float2*)(g + ((size_t)(b * 32 + cin) * HG + gy) * WG + gxa);
        int slot = cin >> 3, elem = cin & 7;
        if (c2 > 0) {
            int wch = c2 - 1;
            gl[1][wr][wch][((slot ^ ((wch >> 1) & 3)) << 3) + elem] = (_Float16)v.x;
        }
        {
            int wch = c2;
            gl[0][wr][wch][((slot ^ ((wch >> 1) & 3)) << 3) + elem] = (_Float16)v.y;
        }
    }

    const int lane = tid & 63, w = tid >> 6;
    const int c = lane & 15, grp = lane >> 4;

    const _Float16* w1p = (const _Float16*)ws_w1 + lane * 8;
    half8 bf[4];
#pragma unroll
    for (int nt = 0; nt < 4; ++nt) bf[nt] = *(const half8*)(w1p + nt * 512);

    f32x4 zf = {0.f, 0.f, 0.f, 0.f};
    f32x4 acc[2][4];
#pragma unroll
    for (int mt = 0; mt < 2; ++mt)
#pragma unroll
        for (int nt = 0; nt < 4; ++nt) acc[mt][nt] = zf;

    __syncthreads();   // gl ready; no further barriers

#pragma unroll
    for (int s = 0; s < 9; ++s) {
        const int dy = s / 3, dx = s - dy * 3;
        const int par = dx & 1, dxh = dx >> 1;
        half8 af[2];
#pragma unroll
        for (int mt = 0; mt < 2; ++mt) {
            int wr = 2 * (2 * w + mt) + dy;
            int wch = c + dxh;
            af[mt] = *(const half8*)&gl[par][wr][wch][(grp ^ ((wch >> 1) & 3)) << 3];
        }
        const _Float16* wnext = w1p + (size_t)(s + 1) * 2048;
#pragma unroll
        for (int nt = 0; nt < 4; ++nt) {
            half8 cur = bf[nt];
            bf[nt] = *(const half8*)(wnext + nt * 512);   // s=8 overread harmless
            acc[0][nt] = __builtin_amdgcn_mfma_f32_16x16x32_f16(af[0], cur, acc[0][nt], 0, 0, 0);
            acc[1][nt] = __builtin_amdgcn_mfma_f32_16x16x32_f16(af[1], cur, acc[1][nt], 0, 0, 0);
        }
    }

#pragma unroll
    for (int nt = 0; nt < 4; ++nt) {
        int ch = nt * 16 + c;
        float mu = mean[ch], scv = rsqrtf(var[ch] + 1e-5f) * gamma[ch], bt = beta[ch];
#pragma unroll
        for (int mt = 0; mt < 2; ++mt) {
            int y = ty0 + 2 * w + mt;
#pragma unroll
            for (int r = 0; r < 4; ++r) {
                int x = tx0 + grp * 4 + r;
                float v = fmaxf((acc[mt][nt][r] - mu) * scv + bt, 0.f);
                xg[(((size_t)(b * H + y) * W + x) << 6) + ch] = (_Float16)v;
            }
        }
    }
}

// ---------------------------------------------------------------------------
// conv2 (3x3 s1 p1, 64->576) + softmax(9) + convex combine + pixel shuffle.
// PERSISTENT R16 engine: 512 blocks (2/CU), tiles bid, bid+512, ... Per
// tile: 16x4 px, 4 waves (wave = ng, k-complete per lane -> lane-local
// softmax), Mt=4, register-direct B stream, ring-offset K order, no K-loop
// barriers, s_setprio around MFMA clusters, fully unrolled ring loop.
// NEW vs R16: epilogue loads each lane's 3x6 d8s patch ONCE per mt via
// vector LDS reads (24 reads/wave-tile vs 144 scalar); d8s rows padded to
// 24 floats for 16B-aligned float4 reads.
// ---------------------------------------------------------------------------
__global__ __launch_bounds__(256, 2) void conv2_mfma(
    const _Float16* __restrict__ xg, const char* __restrict__ ws_c,
    const float* __restrict__ disp, float* __restrict__ out)
{
    __shared__ __align__(16) _Float16 xs[108 * 64];   // 6r x 18c x 64ch, 13824 B
    __shared__ __align__(16) float d8s[6 * 24];       // rows padded 18->24
    const int tid = threadIdx.x;
    const int lane = tid & 63, wid = tid >> 6;
    const int c = lane & 15, grp = lane >> 4;

    // this wave's weight stream: [18 s][9 k][1024B], lane slice = lane*16 B
    const _Float16* wp = (const _Float16*)ws_c + (size_t)wid * 82944 + lane * 8;

    half8 zero8;
#pragma unroll
    for (int j = 0; j < 8; ++j) zero8[j] = (_Float16)0.f;

    for (int tile = blockIdx.x; tile < 1600; tile += 512) {
        const int b   = tile / 200;
        const int rem = tile - b * 200;
        const int tyi = rem / 10;
        const int tx0 = (rem - tyi * 10) * 16, ty0 = tyi * 4;
        const int s0  = (tile * 7) % 18;

        __syncthreads();   // guard xs/d8s overwrite vs prior tile's readers

        // stage x window 6x18x64 f16, swizzled: 16B slot' = slot ^ (wp&7)
        for (int cidx = tid; cidx < 864; cidx += 256) {
            int wpx = cidx >> 3, slot = cidx & 7;
            int rr = wpx / 18, cc = wpx - rr * 18;
            int y = ty0 - 1 + rr, xc = tx0 - 1 + cc;
            half8 v = zero8;
            if (y >= 0 && y < H && xc >= 0 && xc < W)
                v = *(const half8*)(xg + (((size_t)(b * H + y) * W + xc) << 6) + slot * 8);
            *(half8*)&xs[wpx * 64 + (slot ^ (wpx & 7)) * 8] = v;
        }
        if (tid < 108) {
            int rr = tid / 18, cc = tid - rr * 18;
            int y = ty0 - 1 + rr, xc = tx0 - 1 + cc;
            float v = 0.f;
            if (y >= 0 && y < H && xc >= 0 && xc < W) v = 8.f * disp[(b * H + y) * W + xc];
            d8s[rr * 24 + cc] = v;
        }

        f32x4 zf = {0.f, 0.f, 0.f, 0.f};
        f32x4 acc[4][9];
#pragma unroll
        for (int m = 0; m < 4; ++m)
#pragma unroll
            for (int k = 0; k < 9; ++k) acc[m][k] = zf;

        half8 bf[9];
#pragma unroll
        for (int k = 0; k < 9; ++k)
            bf[k] = *(const half8*)(wp + (size_t)s0 * 4608 + k * 512);

        __syncthreads();   // xs, d8s ready

        int s = s0;
#pragma unroll
        for (int i = 0; i < 18; ++i) {
            int sn = s + 1; if (sn == 18) sn = 0;
            const int t = s >> 1;
            const int dy = t / 3, dx = t - dy * 3;
            const int aslot = (s & 1) * 4 + grp;
            half8 af[4];
#pragma unroll
            for (int mt = 0; mt < 4; ++mt) {
                int wrow = (mt + dy) * 18 + c + dx;
                af[mt] = *(const half8*)&xs[wrow * 64 + (aslot ^ (wrow & 7)) * 8];
            }
            const _Float16* wnext = wp + (size_t)sn * 4608;
            __builtin_amdgcn_s_setprio(1);
#pragma unroll
            for (int k = 0; k < 9; ++k) {
                half8 cur = bf[k];
                // prefetch ring-next step's fragment k (wrap load unused, valid)
                bf[k] = *(const half8*)(wnext + k * 512);
#pragma unroll
                for (int mt = 0; mt < 4; ++mt)
                    acc[mt][k] = __builtin_amdgcn_mfma_f32_16x16x32_f16(
                        af[mt], cur, acc[mt][k], 0, 0, 0);
            }
            __builtin_amdgcn_s_setprio(0);
            s = sn;
        }

        // epilogue: lane-local softmax over 9 k per (pixel, ij).
        // Each lane needs only the 3x6 d8s patch rows mt..mt+2, cols
        // c0..c0+5 -> load once per mt as float4+float2 (16B-aligned via
        // 24-float row stride; group-broadcast reads, conflict-free).
        const int ij = wid * 16 + c;
        const int oi = ij >> 3, oj = ij & 7;
        const int c0 = grp * 4;
#pragma unroll
        for (int mt = 0; mt < 4; ++mt) {
            float p[3][6];
#pragma unroll
            for (int ky = 0; ky < 3; ++ky) {
                float4 q0 = *(const float4*)&d8s[(mt + ky) * 24 + c0];
                float2 q1 = *(const float2*)&d8s[(mt + ky) * 24 + c0 + 4];
                p[ky][0] = q0.x; p[ky][1] = q0.y; p[ky][2] = q0.z; p[ky][3] = q0.w;
                p[ky][4] = q1.x; p[ky][5] = q1.y;
            }
#pragma unroll
            for (int r = 0; r < 4; ++r) {
                float mx = acc[mt][0][r];
#pragma unroll
                for (int k9 = 1; k9 < 9; ++k9) mx = fmaxf(mx, acc[mt][k9][r]);
                float sum = 0.f, up = 0.f;
#pragma unroll
                for (int k9 = 0; k9 < 9; ++k9) {
                    float e = __expf(acc[mt][k9][r] - mx);
                    sum += e; up += e * p[k9 / 3][r + k9 % 3];
                }
                int y = ty0 + mt, xc = tx0 + c0 + r;
                out[((size_t)(b * (8 * H) + y * 8 + oi)) * (size_t)(8 * W) + xc * 8 + oj] = up / sum;
            }
        }
    }
}

// ---------------------------------------------------------------------------
extern "C" void kernel_launch(void* const* d_in, const int* in_sizes, int n_in,
                              void* d_out, int out_size, void* d_ws, size_t ws_size,
                              hipStream_t stream)
{
    const float* guidance = (const float*)d_in[0];
    const float* disp     = (const float*)d_in[1];
    const float* conv1_w  = (const float*)d_in[2];
    const float* bn_gamma = (const float*)d_in[3];
    const float* bn_beta  = (const float*)d_in[4];
    const float* bn_mean  = (const float*)d_in[5];
    const float* bn_var   = (const float*)d_in[6];
    const float* conv2_w  = (const float*)d_in[7];
    float* out = (float*)d_out;
    char* ws = (char*)d_ws;
    _Float16* xg = (_Float16*)(ws + XG_OFF);

    prep<<<dim3((576 * 64 + 64 * 32 + 255) / 256), dim3(256), 0, stream>>>(
        conv1_w, conv2_w, ws);
    dim3 grid1(W / 16, H / 8, B_);   // (10, 10, 8)
    conv1_mfma<<<grid1, dim3(256), 0, stream>>>(
        guidance, ws + W1WS_OFF, bn_gamma, bn_beta, bn_mean, bn_var, xg);
    conv2_mfma<<<dim3(512), dim3(256), 0, stream>>>(
        xg, ws + CWS_OFF, disp, out);
}